// Round 1
// baseline (2749.529 us; speedup 1.0000x reference)
//
#include <hip/hip_runtime.h>

#define N_NODES 50000
#define N_EDGES 400000
#define N_GRAPHS 64
#define EMB 64
#define H 128
#define EPS 1e-5f

// ---------------- CSR build ----------------

__global__ void count_deg_kernel(const int* __restrict__ dst, int* __restrict__ deg) {
    int rel = blockIdx.y;
    int e = blockIdx.x * 256 + threadIdx.x;
    if (e < N_EDGES) atomicAdd(&deg[rel * N_NODES + dst[rel * N_EDGES + e]], 1);
}

__global__ void scan_kernel(const int* __restrict__ deg, int* __restrict__ row_ptr) {
    int rel = blockIdx.x;
    const int* d = deg + rel * N_NODES;
    int* rp = row_ptr + rel * (N_NODES + 1);
    __shared__ int sm[1024];
    __shared__ int carry;
    if (threadIdx.x == 0) carry = 0;
    __syncthreads();
    for (int base = 0; base < N_NODES; base += 1024) {
        int i = base + (int)threadIdx.x;
        int v = (i < N_NODES) ? d[i] : 0;
        sm[threadIdx.x] = v;
        __syncthreads();
        for (int off = 1; off < 1024; off <<= 1) {
            int t = (threadIdx.x >= off) ? sm[threadIdx.x - off] : 0;
            __syncthreads();
            sm[threadIdx.x] += t;
            __syncthreads();
        }
        int incl = sm[threadIdx.x];
        if (i < N_NODES) rp[i] = carry + incl - v;   // exclusive prefix
        __syncthreads();
        if (threadIdx.x == 1023) carry += incl;      // incl of tid 1023 == chunk total
        __syncthreads();
    }
    if (threadIdx.x == 0) rp[N_NODES] = carry;
}

__global__ void init_cur_kernel(const int* __restrict__ row_ptr, int* __restrict__ cur) {
    int i = blockIdx.x * 256 + threadIdx.x;
    if (i < 3 * N_NODES) {
        int rel = i / N_NODES, n = i - rel * N_NODES;
        cur[i] = row_ptr[rel * (N_NODES + 1) + n];
    }
}

__global__ void fill_kernel(const int* __restrict__ src, const int* __restrict__ dst,
                            int* __restrict__ cur, int* __restrict__ edge_src) {
    int rel = blockIdx.y;
    int e = blockIdx.x * 256 + threadIdx.x;
    if (e < N_EDGES) {
        int dn = dst[rel * N_EDGES + e];
        int pos = atomicAdd(&cur[rel * N_NODES + dn], 1);
        edge_src[rel * N_EDGES + pos] = src[rel * N_EDGES + e];
    }
}

// ---------------- Embedding gather ----------------

__global__ void embed_kernel(const int* __restrict__ h_idx, const int* __restrict__ p_idx,
                             const int* __restrict__ hp_idx,
                             const float* __restrict__ emb_h, const float* __restrict__ emb_p,
                             const float* __restrict__ emb_hp,
                             float* __restrict__ x) {
    int rel = blockIdx.y;
    int i = blockIdx.x * 256 + threadIdx.x;  // over N*EMB
    if (i >= N_NODES * EMB) return;
    int n = i / EMB, c = i - n * EMB;
    const int* idx = rel == 0 ? h_idx : (rel == 1 ? p_idx : hp_idx);
    const float* emb = rel == 0 ? emb_h : (rel == 1 ? emb_p : emb_hp);
    x[(size_t)rel * N_NODES * EMB + i] = emb[idx[n] * EMB + c];
}

// ---------------- Neighbor mean aggregation (CSR gather) ----------------

template <int DIN>
__global__ void aggregate_kernel(const float* __restrict__ x, int ldx,
                                 const int* __restrict__ row_ptr,
                                 const int* __restrict__ edge_src,
                                 float* __restrict__ nmean /* ld = H always */) {
    int rel = blockIdx.y;
    const int NPB = 256 / DIN;
    int node = blockIdx.x * NPB + threadIdx.x / DIN;
    int c = threadIdx.x % DIN;
    if (node >= N_NODES) return;
    const int* rp = row_ptr + rel * (N_NODES + 1);
    const int* es = edge_src + rel * N_EDGES;
    const float* xr = x + (size_t)rel * N_NODES * ldx;
    int s0 = rp[node], s1 = rp[node + 1];
    float sum = 0.f;
    for (int e = s0; e < s1; e++)
        sum += xr[(size_t)es[e] * ldx + c];
    float dg = (float)max(s1 - s0, 1);
    nmean[((size_t)rel * N_NODES + node) * H + c] = sum / dg;
}

// ---------------- Fused GEMM: out = x@Ws + nmean@Wn + b, PReLU ----------------
// Block: 128 rows x 128 cols, 256 threads, 8x8 micro-tile (split 4+4 at distance 64).
// out may alias nmean (each block reads only its own 128 rows before storing).

template <int KX>
__global__ __launch_bounds__(256) void gemm_kernel(
    const float* __restrict__ x, int ldx,
    const float* __restrict__ nmean,
    const float* __restrict__ Wself, const float* __restrict__ Wneigh,
    const float* __restrict__ bias, const float* __restrict__ alpha,
    float* __restrict__ out) {
    int rel = blockIdx.y;
    int row0 = blockIdx.x * 128;
    const float* Ws = Wself + (size_t)rel * KX * H;
    const float* Wn = Wneigh + (size_t)rel * KX * H;
    const float* xr = x + (size_t)rel * N_NODES * ldx;
    const float* nm = nmean + (size_t)rel * N_NODES * H;
    float* o = out + (size_t)rel * N_NODES * H;

    __shared__ __align__(16) float At[32][132];  // transposed A chunk, pad 132 (528B rows, 16B-aligned)
    __shared__ __align__(16) float Wl[32][128];

    float acc[8][8];
#pragma unroll
    for (int i = 0; i < 8; i++)
#pragma unroll
        for (int j = 0; j < 8; j++) acc[i][j] = 0.f;

    int tid = threadIdx.x;
    int tx = tid & 15, ty = tid >> 4;

    for (int kc = 0; kc < 2 * KX; kc += 32) {
        const bool isSelf = kc < KX;
        const float* A = isSelf ? xr : nm;
        int lda = isSelf ? ldx : H;
        int kbase = isSelf ? kc : kc - KX;
        const float* W = isSelf ? Ws : Wn;
        // A tile: 128 rows x 32 k, stored transposed
#pragma unroll
        for (int it = 0; it < 4; it++) {
            int r = it * 32 + (tid >> 3);
            int k4 = (tid & 7) * 4;
            int grow = row0 + r;
            float4 v = make_float4(0.f, 0.f, 0.f, 0.f);
            if (grow < N_NODES) v = *(const float4*)&A[(size_t)grow * lda + kbase + k4];
            At[k4 + 0][r] = v.x;
            At[k4 + 1][r] = v.y;
            At[k4 + 2][r] = v.z;
            At[k4 + 3][r] = v.w;
        }
        // W tile: 32 k x 128 cols
#pragma unroll
        for (int it = 0; it < 4; it++) {
            int k = it * 8 + (tid >> 5);
            int c4 = (tid & 31) * 4;
            *(float4*)&Wl[k][c4] = *(const float4*)&W[(size_t)(kbase + k) * H + c4];
        }
        __syncthreads();
#pragma unroll 8
        for (int k = 0; k < 32; k++) {
            float a0[8], w0[8];
            *(float4*)&a0[0] = *(const float4*)&At[k][ty * 4];
            *(float4*)&a0[4] = *(const float4*)&At[k][ty * 4 + 64];
            *(float4*)&w0[0] = *(const float4*)&Wl[k][tx * 4];
            *(float4*)&w0[4] = *(const float4*)&Wl[k][tx * 4 + 64];
#pragma unroll
            for (int i = 0; i < 8; i++)
#pragma unroll
                for (int j = 0; j < 8; j++) acc[i][j] += a0[i] * w0[j];
        }
        __syncthreads();
    }

    const float* bb = bias + rel * H;
    const float* aa = alpha + rel * H;
#pragma unroll
    for (int i = 0; i < 8; i++) {
        int r = row0 + ty * 4 + (i < 4 ? i : 60 + i);  // i>=4: +64 offset
        if (r >= N_NODES) continue;
#pragma unroll
        for (int jb = 0; jb < 2; jb++) {
            int cbase = tx * 4 + jb * 64;
            float4 v;
            float* vp = &v.x;
#pragma unroll
            for (int j = 0; j < 4; j++) {
                float val = acc[i][jb * 4 + j] + bb[cbase + j];
                vp[j] = val > 0.f ? val : aa[cbase + j] * val;
            }
            *(float4*)&o[(size_t)r * H + cbase] = v;
        }
    }
}

// ---------------- BatchNorm ----------------

__global__ void bn_stats_kernel(const float* __restrict__ h, float* __restrict__ stats) {
    int rel = blockIdx.y;
    int c = threadIdx.x & (H - 1);
    int half = threadIdx.x >> 7;  // 0/1
    const float* hp = h + (size_t)rel * N_NODES * H;
    int r0 = blockIdx.x * 512 + half;
    int r1 = min(blockIdx.x * 512 + 512, N_NODES);
    float s = 0.f, ss = 0.f;
    for (int r = r0; r < r1; r += 2) {
        float v = hp[(size_t)r * H + c];
        s += v;
        ss += v * v;
    }
    __shared__ float sm[512];
    sm[threadIdx.x] = s;
    sm[256 + threadIdx.x] = ss;
    __syncthreads();
    if (half == 0) {
        s += sm[threadIdx.x + 128];
        ss += sm[256 + threadIdx.x + 128];
        atomicAdd(&stats[rel * 256 + c], s);
        atomicAdd(&stats[rel * 256 + 128 + c], ss);
    }
}

__global__ void bn_apply_kernel(float* __restrict__ h, const float* __restrict__ stats,
                                const float* __restrict__ gamma, const float* __restrict__ beta) {
    int rel = blockIdx.y;
    size_t i4 = (size_t)blockIdx.x * 256 + threadIdx.x;
    if (i4 >= (size_t)N_NODES * H / 4) return;
    size_t i = i4 * 4;
    int c = (int)(i % H);
    float* hp = h + (size_t)rel * N_NODES * H;
    const float inv = 1.f / N_NODES;
    float4 v = *(float4*)&hp[i];
    float* vv = &v.x;
#pragma unroll
    for (int j = 0; j < 4; j++) {
        int cc = c + j;
        float mu = stats[rel * 256 + cc] * inv;
        float var = stats[rel * 256 + 128 + cc] * inv - mu * mu;
        vv[j] = gamma[rel * H + cc] * (vv[j] - mu) * rsqrtf(var + EPS) + beta[rel * H + cc];
    }
    *(float4*)&hp[i] = v;
}

// ---------------- Per-graph mean readout ----------------

__global__ void readout_kernel(const float* __restrict__ h, const int* __restrict__ seg,
                               float* __restrict__ out, int layer) {
    int g = blockIdx.x;
    int rel = blockIdx.y;
    int c = threadIdx.x;  // 128
    const int* sg = seg + rel * N_NODES;
    int lo = 0, hi = N_NODES;
    while (lo < hi) { int m = (lo + hi) >> 1; if (sg[m] < g) lo = m + 1; else hi = m; }
    int start = lo;
    hi = N_NODES;
    while (lo < hi) { int m = (lo + hi) >> 1; if (sg[m] <= g) lo = m + 1; else hi = m; }
    int end = lo;
    const float* hp = h + (size_t)rel * N_NODES * H;
    float s = 0.f;
    for (int r = start; r < end; r++) s += hp[(size_t)r * H + c];
    int cnt = end - start;
    float denom = (float)max(cnt, 1);
    out[g * (3 * 4 * H) + rel * (4 * H) + layer * H + c] = s / denom;
}

// ---------------- Orchestration ----------------

extern "C" void kernel_launch(void* const* d_in, const int* in_sizes, int n_in,
                              void* d_out, int out_size, void* d_ws, size_t ws_size,
                              hipStream_t stream) {
    const int* h_idx = (const int*)d_in[0];
    const int* p_idx = (const int*)d_in[1];
    const int* hp_idx = (const int*)d_in[2];
    const int* src = (const int*)d_in[3];
    const int* dst = (const int*)d_in[4];
    const int* seg = (const int*)d_in[5];
    const float* emb_h = (const float*)d_in[6];
    const float* emb_p = (const float*)d_in[7];
    const float* emb_hp = (const float*)d_in[8];
    const float* W1_self = (const float*)d_in[9];
    const float* W1_neigh = (const float*)d_in[10];
    const float* b1 = (const float*)d_in[11];
    const float* a1 = (const float*)d_in[12];
    const float* gamma1 = (const float*)d_in[13];
    const float* beta1 = (const float*)d_in[14];
    const float* W_self = (const float*)d_in[15];
    const float* W_neigh = (const float*)d_in[16];
    const float* b = (const float*)d_in[17];
    const float* a = (const float*)d_in[18];
    const float* gamma = (const float*)d_in[19];
    const float* beta = (const float*)d_in[20];
    float* out = (float*)d_out;

    // workspace layout (~160.5 MB total)
    char* p = (char*)d_ws;
    float* hA = (float*)p; p += (size_t)3 * N_NODES * H * sizeof(float);  // 76.8 MB
    float* hB = (float*)p; p += (size_t)3 * N_NODES * H * sizeof(float);  // 76.8 MB
    int* deg = (int*)p; p += (size_t)3 * N_NODES * 4;
    int* row_ptr = (int*)p; p += (size_t)3 * (N_NODES + 1) * 4;
    int* cur = (int*)p; p += (size_t)3 * N_NODES * 4;
    int* edge_src = (int*)p; p += (size_t)3 * N_EDGES * 4;
    float* stats = (float*)p; p += 3 * 256 * sizeof(float);

    // CSR build (per call; inputs are constant so result is the same each call)
    hipMemsetAsync(deg, 0, (size_t)3 * N_NODES * 4, stream);
    dim3 eb((N_EDGES + 255) / 256, 3);
    count_deg_kernel<<<eb, 256, 0, stream>>>(dst, deg);
    scan_kernel<<<3, 1024, 0, stream>>>(deg, row_ptr);
    init_cur_kernel<<<(3 * N_NODES + 255) / 256, 256, 0, stream>>>(row_ptr, cur);
    fill_kernel<<<eb, 256, 0, stream>>>(src, dst, cur, edge_src);

    // x0 = embedding lookups (ld = EMB = 64), stored in hA
    embed_kernel<<<dim3((N_NODES * EMB + 255) / 256, 3), 256, 0, stream>>>(
        h_idx, p_idx, hp_idx, emb_h, emb_p, emb_hp, hA);

    dim3 gemm_grid((N_NODES + 127) / 128, 3);
    dim3 bn_stats_grid((N_NODES + 511) / 512, 3);
    dim3 bn_apply_grid(N_NODES * H / 4 / 256, 3);
    dim3 readout_grid(N_GRAPHS, 3);

    // ---- layer 1 (K = 64) ----
    aggregate_kernel<64><<<dim3((N_NODES + 3) / 4, 3), 256, 0, stream>>>(hA, EMB, row_ptr, edge_src, hB);
    gemm_kernel<64><<<gemm_grid, 256, 0, stream>>>(hA, EMB, hB, W1_self, W1_neigh, b1, a1, hB);
    hipMemsetAsync(stats, 0, 3 * 256 * 4, stream);
    bn_stats_kernel<<<bn_stats_grid, 256, 0, stream>>>(hB, stats);
    bn_apply_kernel<<<bn_apply_grid, 256, 0, stream>>>(hB, stats, gamma1, beta1);
    readout_kernel<<<readout_grid, 128, 0, stream>>>(hB, seg, out, 0);

    // ---- layers 2-4 (K = 128) ----
    float* xin = hB;
    float* xout = hA;
    for (int l = 0; l < 3; l++) {
        aggregate_kernel<128><<<dim3((N_NODES + 1) / 2, 3), 256, 0, stream>>>(xin, H, row_ptr, edge_src, xout);
        gemm_kernel<128><<<gemm_grid, 256, 0, stream>>>(
            xin, H, xout,
            W_self + (size_t)l * 3 * H * H, W_neigh + (size_t)l * 3 * H * H,
            b + l * 3 * H, a + l * 3 * H, xout);
        hipMemsetAsync(stats, 0, 3 * 256 * 4, stream);
        bn_stats_kernel<<<bn_stats_grid, 256, 0, stream>>>(xout, stats);
        bn_apply_kernel<<<bn_apply_grid, 256, 0, stream>>>(xout, stats, gamma + l * 3 * H, beta + l * 3 * H);
        readout_kernel<<<readout_grid, 128, 0, stream>>>(xout, seg, out, l + 1);
        float* t = xin; xin = xout; xout = t;
    }
}

// Round 2
// 1385.385 us; speedup vs baseline: 1.9847x; 1.9847x over previous
//
#include <hip/hip_runtime.h>

#define N_NODES 50000
#define N_EDGES 400000
#define N_GRAPHS 64
#define EMB 64
#define H 128
#define EPS 1e-5f

// ---------------- CSR build ----------------

__global__ void count_deg_kernel(const int* __restrict__ dst, int* __restrict__ deg) {
    int rel = blockIdx.y;
    int e = blockIdx.x * 256 + threadIdx.x;
    if (e < N_EDGES) atomicAdd(&deg[rel * N_NODES + dst[rel * N_EDGES + e]], 1);
}

__global__ void scan_kernel(const int* __restrict__ deg, int* __restrict__ row_ptr) {
    int rel = blockIdx.x;
    const int* d = deg + rel * N_NODES;
    int* rp = row_ptr + rel * (N_NODES + 1);
    __shared__ int sm[1024];
    __shared__ int carry;
    if (threadIdx.x == 0) carry = 0;
    __syncthreads();
    for (int base = 0; base < N_NODES; base += 1024) {
        int i = base + (int)threadIdx.x;
        int v = (i < N_NODES) ? d[i] : 0;
        sm[threadIdx.x] = v;
        __syncthreads();
        for (int off = 1; off < 1024; off <<= 1) {
            int t = (threadIdx.x >= off) ? sm[threadIdx.x - off] : 0;
            __syncthreads();
            sm[threadIdx.x] += t;
            __syncthreads();
        }
        int incl = sm[threadIdx.x];
        if (i < N_NODES) rp[i] = carry + incl - v;   // exclusive prefix
        __syncthreads();
        if (threadIdx.x == 1023) carry += incl;      // incl of tid 1023 == chunk total
        __syncthreads();
    }
    if (threadIdx.x == 0) rp[N_NODES] = carry;
}

__global__ void init_cur_kernel(const int* __restrict__ row_ptr, int* __restrict__ cur) {
    int i = blockIdx.x * 256 + threadIdx.x;
    if (i < 3 * N_NODES) {
        int rel = i / N_NODES, n = i - rel * N_NODES;
        cur[i] = row_ptr[rel * (N_NODES + 1) + n];
    }
}

__global__ void fill_kernel(const int* __restrict__ src, const int* __restrict__ dst,
                            int* __restrict__ cur, int* __restrict__ edge_src) {
    int rel = blockIdx.y;
    int e = blockIdx.x * 256 + threadIdx.x;
    if (e < N_EDGES) {
        int dn = dst[rel * N_EDGES + e];
        int pos = atomicAdd(&cur[rel * N_NODES + dn], 1);
        edge_src[rel * N_EDGES + pos] = src[rel * N_EDGES + e];
    }
}

// ---------------- Embedding gather (float4) ----------------

__global__ void embed_kernel(const int* __restrict__ h_idx, const int* __restrict__ p_idx,
                             const int* __restrict__ hp_idx,
                             const float* __restrict__ emb_h, const float* __restrict__ emb_p,
                             const float* __restrict__ emb_hp,
                             float* __restrict__ x) {
    int rel = blockIdx.y;
    int i = blockIdx.x * 256 + threadIdx.x;  // float4 units over N*EMB/4
    if (i >= N_NODES * EMB / 4) return;
    int n = i / (EMB / 4), c4 = (i % (EMB / 4)) * 4;
    const int* idx = rel == 0 ? h_idx : (rel == 1 ? p_idx : hp_idx);
    const float* emb = rel == 0 ? emb_h : (rel == 1 ? emb_p : emb_hp);
    *(float4*)&x[(size_t)rel * N_NODES * EMB + (size_t)n * EMB + c4] =
        *(const float4*)&emb[(size_t)idx[n] * EMB + c4];
}

// ---------------- Neighbor mean aggregation (CSR gather, float4, unroll-4) ----------------

template <int DIN>
__global__ __launch_bounds__(256) void aggregate_kernel(
        const float* __restrict__ x, int ldx,
        const int* __restrict__ row_ptr, const int* __restrict__ edge_src,
        float* __restrict__ nmean /* ld = H always */) {
    const int TPN = DIN / 4;                 // threads per node (float4 each)
    int rel = blockIdx.y;
    int node = blockIdx.x * (256 / TPN) + threadIdx.x / TPN;
    int c4 = (threadIdx.x % TPN) * 4;
    if (node >= N_NODES) return;
    const int* rp = row_ptr + rel * (N_NODES + 1);
    const int* es = edge_src + rel * N_EDGES;
    const float* xr = x + (size_t)rel * N_NODES * ldx;
    int s0 = rp[node], s1 = rp[node + 1];
    float4 acc = make_float4(0.f, 0.f, 0.f, 0.f);
    int e = s0;
    for (; e + 4 <= s1; e += 4) {
        int i0 = es[e], i1 = es[e + 1], i2 = es[e + 2], i3 = es[e + 3];
        float4 v0 = *(const float4*)&xr[(size_t)i0 * ldx + c4];
        float4 v1 = *(const float4*)&xr[(size_t)i1 * ldx + c4];
        float4 v2 = *(const float4*)&xr[(size_t)i2 * ldx + c4];
        float4 v3 = *(const float4*)&xr[(size_t)i3 * ldx + c4];
        acc.x += (v0.x + v1.x) + (v2.x + v3.x);
        acc.y += (v0.y + v1.y) + (v2.y + v3.y);
        acc.z += (v0.z + v1.z) + (v2.z + v3.z);
        acc.w += (v0.w + v1.w) + (v2.w + v3.w);
    }
    for (; e < s1; e++) {
        int i0 = es[e];
        float4 v0 = *(const float4*)&xr[(size_t)i0 * ldx + c4];
        acc.x += v0.x; acc.y += v0.y; acc.z += v0.z; acc.w += v0.w;
    }
    float inv = 1.f / (float)max(s1 - s0, 1);
    acc.x *= inv; acc.y *= inv; acc.z *= inv; acc.w *= inv;
    *(float4*)&nmean[((size_t)rel * N_NODES + node) * H + c4] = acc;
}

// ---- Fused GEMM: out = PReLU(x@Ws + nmean@Wn + b); accumulates BN col stats ----
// Block: 128 rows x 128 cols, 256 threads, 8x8 micro-tile (split 4+4 at distance 64).
// out may alias nmean (each block reads only its own 128 rows before storing).

template <int KX>
__global__ __launch_bounds__(256) void gemm_kernel(
    const float* __restrict__ x, int ldx,
    const float* __restrict__ nmean,
    const float* __restrict__ Wself, const float* __restrict__ Wneigh,
    const float* __restrict__ bias, const float* __restrict__ alpha,
    float* __restrict__ out, float* __restrict__ stats) {
    int rel = blockIdx.y;
    int row0 = blockIdx.x * 128;
    const float* Ws = Wself + (size_t)rel * KX * H;
    const float* Wn = Wneigh + (size_t)rel * KX * H;
    const float* xr = x + (size_t)rel * N_NODES * ldx;
    const float* nm = nmean + (size_t)rel * N_NODES * H;
    float* o = out + (size_t)rel * N_NODES * H;

    __shared__ __align__(16) float At[32][132];  // transposed A chunk, pad 132
    __shared__ __align__(16) float Wl[32][128];

    float acc[8][8];
#pragma unroll
    for (int i = 0; i < 8; i++)
#pragma unroll
        for (int j = 0; j < 8; j++) acc[i][j] = 0.f;

    int tid = threadIdx.x;
    int tx = tid & 15, ty = tid >> 4;

    for (int kc = 0; kc < 2 * KX; kc += 32) {
        const bool isSelf = kc < KX;
        const float* A = isSelf ? xr : nm;
        int lda = isSelf ? ldx : H;
        int kbase = isSelf ? kc : kc - KX;
        const float* W = isSelf ? Ws : Wn;
#pragma unroll
        for (int it = 0; it < 4; it++) {
            int r = it * 32 + (tid >> 3);
            int k4 = (tid & 7) * 4;
            int grow = row0 + r;
            float4 v = make_float4(0.f, 0.f, 0.f, 0.f);
            if (grow < N_NODES) v = *(const float4*)&A[(size_t)grow * lda + kbase + k4];
            At[k4 + 0][r] = v.x;
            At[k4 + 1][r] = v.y;
            At[k4 + 2][r] = v.z;
            At[k4 + 3][r] = v.w;
        }
#pragma unroll
        for (int it = 0; it < 4; it++) {
            int k = it * 8 + (tid >> 5);
            int c4 = (tid & 31) * 4;
            *(float4*)&Wl[k][c4] = *(const float4*)&W[(size_t)(kbase + k) * H + c4];
        }
        __syncthreads();
#pragma unroll 8
        for (int k = 0; k < 32; k++) {
            float a0[8], w0[8];
            *(float4*)&a0[0] = *(const float4*)&At[k][ty * 4];
            *(float4*)&a0[4] = *(const float4*)&At[k][ty * 4 + 64];
            *(float4*)&w0[0] = *(const float4*)&Wl[k][tx * 4];
            *(float4*)&w0[4] = *(const float4*)&Wl[k][tx * 4 + 64];
#pragma unroll
            for (int i = 0; i < 8; i++)
#pragma unroll
                for (int j = 0; j < 8; j++) acc[i][j] += a0[i] * w0[j];
        }
        __syncthreads();
    }

    const float* bb = bias + rel * H;
    const float* aa = alpha + rel * H;
    float colsum[8], colssq[8];
#pragma unroll
    for (int j = 0; j < 8; j++) { colsum[j] = 0.f; colssq[j] = 0.f; }

#pragma unroll
    for (int i = 0; i < 8; i++) {
        int r = row0 + ty * 4 + (i < 4 ? i : 60 + i);  // i>=4: +64 offset
        bool valid = r < N_NODES;
#pragma unroll
        for (int jb = 0; jb < 2; jb++) {
            int cbase = tx * 4 + jb * 64;
            float4 v;
            float* vp = &v.x;
#pragma unroll
            for (int j = 0; j < 4; j++) {
                float val = acc[i][jb * 4 + j] + bb[cbase + j];
                val = val > 0.f ? val : aa[cbase + j] * val;
                vp[j] = val;
                if (valid) { colsum[jb * 4 + j] += val; colssq[jb * 4 + j] += val * val; }
            }
            if (valid) *(float4*)&o[(size_t)r * H + cbase] = v;
        }
    }

    // block-reduce column stats in reused LDS, then atomicAdd to global
    float* smS = (float*)&At[0][0];  // 16*128 floats (8 KB) fits in At
    float* smQ = (float*)&Wl[0][0];
#pragma unroll
    for (int jb = 0; jb < 2; jb++)
#pragma unroll
        for (int j = 0; j < 4; j++) {
            int col = tx * 4 + jb * 64 + j;
            smS[ty * 128 + col] = colsum[jb * 4 + j];
            smQ[ty * 128 + col] = colssq[jb * 4 + j];
        }
    for (int off = 8; off > 0; off >>= 1) {
        __syncthreads();
        if (ty < off) {
#pragma unroll
            for (int jb = 0; jb < 2; jb++)
#pragma unroll
                for (int j = 0; j < 4; j++) {
                    int col = tx * 4 + jb * 64 + j;
                    smS[ty * 128 + col] += smS[(ty + off) * 128 + col];
                    smQ[ty * 128 + col] += smQ[(ty + off) * 128 + col];
                }
        }
    }
    if (ty == 0) {
#pragma unroll
        for (int jb = 0; jb < 2; jb++)
#pragma unroll
            for (int j = 0; j < 4; j++) {
                int col = tx * 4 + jb * 64 + j;
                atomicAdd(&stats[rel * 256 + col], smS[col]);
                atomicAdd(&stats[rel * 256 + 128 + col], smQ[col]);
            }
    }
}

// ---------------- Fused BatchNorm apply + per-graph readout ----------------
// seg is sorted per relation, so each thread's rows walk non-decreasing graph ids;
// run-sum per graph, flush via atomicAdd into zeroed out.

__global__ __launch_bounds__(256) void bn_apply_readout_kernel(
        float* __restrict__ h, const float* __restrict__ stats,
        const float* __restrict__ gamma, const float* __restrict__ beta,
        const int* __restrict__ seg, float* __restrict__ out, int layer) {
    int rel = blockIdx.y;
    int c4 = (threadIdx.x & 31) * 4;
    int roff = threadIdx.x >> 5;             // 0..7
    int row0 = blockIdx.x * 256;
    float* hp = h + (size_t)rel * N_NODES * H;
    const int* sg = seg + rel * N_NODES;
    const float invN = 1.f / N_NODES;
    float gs[4], gb[4];
#pragma unroll
    for (int j = 0; j < 4; j++) {
        int c = c4 + j;
        float mu = stats[rel * 256 + c] * invN;
        float var = stats[rel * 256 + 128 + c] * invN - mu * mu;
        float sc = gamma[rel * H + c] * rsqrtf(var + EPS);
        gs[j] = sc;
        gb[j] = beta[rel * H + c] - mu * sc;
    }
    int curg = -1;
    float4 run = make_float4(0.f, 0.f, 0.f, 0.f);
    int rend = min(row0 + 256, N_NODES);
    for (int r = row0 + roff; r < rend; r += 8) {
        float4 v = *(float4*)&hp[(size_t)r * H + c4];
        v.x = v.x * gs[0] + gb[0];
        v.y = v.y * gs[1] + gb[1];
        v.z = v.z * gs[2] + gb[2];
        v.w = v.w * gs[3] + gb[3];
        *(float4*)&hp[(size_t)r * H + c4] = v;
        int g = sg[r];
        if (g != curg) {
            if (curg >= 0) {
                float* ob = out + curg * (3 * 4 * H) + rel * (4 * H) + layer * H + c4;
                atomicAdd(ob + 0, run.x); atomicAdd(ob + 1, run.y);
                atomicAdd(ob + 2, run.z); atomicAdd(ob + 3, run.w);
            }
            curg = g;
            run = make_float4(0.f, 0.f, 0.f, 0.f);
        }
        run.x += v.x; run.y += v.y; run.z += v.z; run.w += v.w;
    }
    if (curg >= 0) {
        float* ob = out + curg * (3 * 4 * H) + rel * (4 * H) + layer * H + c4;
        atomicAdd(ob + 0, run.x); atomicAdd(ob + 1, run.y);
        atomicAdd(ob + 2, run.z); atomicAdd(ob + 3, run.w);
    }
}

// ---------------- Final scale: divide by per-graph node counts ----------------

__global__ void scale_out_kernel(float* __restrict__ out, const int* __restrict__ seg) {
    int i = blockIdx.x * 256 + threadIdx.x;
    if (i >= N_GRAPHS * 3 * 4 * H) return;
    int g = i / (3 * 4 * H), k = i % (3 * 4 * H), rel = k / (4 * H);
    const int* sg = seg + rel * N_NODES;
    int lo = 0, hi = N_NODES;
    while (lo < hi) { int m = (lo + hi) >> 1; if (sg[m] < g) lo = m + 1; else hi = m; }
    int start = lo;
    hi = N_NODES;
    while (lo < hi) { int m = (lo + hi) >> 1; if (sg[m] <= g) lo = m + 1; else hi = m; }
    int cnt = lo - start;
    out[i] /= (float)max(cnt, 1);
}

// ---------------- Orchestration ----------------

extern "C" void kernel_launch(void* const* d_in, const int* in_sizes, int n_in,
                              void* d_out, int out_size, void* d_ws, size_t ws_size,
                              hipStream_t stream) {
    const int* h_idx = (const int*)d_in[0];
    const int* p_idx = (const int*)d_in[1];
    const int* hp_idx = (const int*)d_in[2];
    const int* src = (const int*)d_in[3];
    const int* dst = (const int*)d_in[4];
    const int* seg = (const int*)d_in[5];
    const float* emb_h = (const float*)d_in[6];
    const float* emb_p = (const float*)d_in[7];
    const float* emb_hp = (const float*)d_in[8];
    const float* W1_self = (const float*)d_in[9];
    const float* W1_neigh = (const float*)d_in[10];
    const float* b1 = (const float*)d_in[11];
    const float* a1 = (const float*)d_in[12];
    const float* gamma1 = (const float*)d_in[13];
    const float* beta1 = (const float*)d_in[14];
    const float* W_self = (const float*)d_in[15];
    const float* W_neigh = (const float*)d_in[16];
    const float* b = (const float*)d_in[17];
    const float* a = (const float*)d_in[18];
    const float* gamma = (const float*)d_in[19];
    const float* beta = (const float*)d_in[20];
    float* out = (float*)d_out;

    // workspace layout
    char* p = (char*)d_ws;
    float* hA = (float*)p; p += (size_t)3 * N_NODES * H * sizeof(float);  // 76.8 MB
    float* hB = (float*)p; p += (size_t)3 * N_NODES * H * sizeof(float);  // 76.8 MB
    int* deg = (int*)p; p += (size_t)3 * N_NODES * 4;
    int* row_ptr = (int*)p; p += (size_t)3 * (N_NODES + 1) * 4;
    int* cur = (int*)p; p += (size_t)3 * N_NODES * 4;
    int* edge_src = (int*)p; p += (size_t)3 * N_EDGES * 4;
    float* stats = (float*)p; p += 3 * 256 * sizeof(float);

    // zero output accumulator (readout accumulates atomically)
    hipMemsetAsync(out, 0, (size_t)N_GRAPHS * 3 * 4 * H * sizeof(float), stream);

    // CSR build
    hipMemsetAsync(deg, 0, (size_t)3 * N_NODES * 4, stream);
    dim3 eb((N_EDGES + 255) / 256, 3);
    count_deg_kernel<<<eb, 256, 0, stream>>>(dst, deg);
    scan_kernel<<<3, 1024, 0, stream>>>(deg, row_ptr);
    init_cur_kernel<<<(3 * N_NODES + 255) / 256, 256, 0, stream>>>(row_ptr, cur);
    fill_kernel<<<eb, 256, 0, stream>>>(src, dst, cur, edge_src);

    // x0 = embedding lookups (ld = EMB = 64), stored in hA
    embed_kernel<<<dim3(N_NODES * EMB / 4 / 256 + 1, 3), 256, 0, stream>>>(
        h_idx, p_idx, hp_idx, emb_h, emb_p, emb_hp, hA);

    dim3 gemm_grid((N_NODES + 127) / 128, 3);
    dim3 bnro_grid((N_NODES + 255) / 256, 3);

    // ---- layer 1 (K = 64) ----
    aggregate_kernel<64><<<dim3((N_NODES + 15) / 16, 3), 256, 0, stream>>>(hA, EMB, row_ptr, edge_src, hB);
    hipMemsetAsync(stats, 0, 3 * 256 * 4, stream);
    gemm_kernel<64><<<gemm_grid, 256, 0, stream>>>(hA, EMB, hB, W1_self, W1_neigh, b1, a1, hB, stats);
    bn_apply_readout_kernel<<<bnro_grid, 256, 0, stream>>>(hB, stats, gamma1, beta1, seg, out, 0);

    // ---- layers 2-4 (K = 128) ----
    float* xin = hB;
    float* xout = hA;
    for (int l = 0; l < 3; l++) {
        aggregate_kernel<128><<<dim3((N_NODES + 7) / 8, 3), 256, 0, stream>>>(xin, H, row_ptr, edge_src, xout);
        hipMemsetAsync(stats, 0, 3 * 256 * 4, stream);
        gemm_kernel<128><<<gemm_grid, 256, 0, stream>>>(
            xin, H, xout,
            W_self + (size_t)l * 3 * H * H, W_neigh + (size_t)l * 3 * H * H,
            b + l * 3 * H, a + l * 3 * H, xout, stats);
        bn_apply_readout_kernel<<<bnro_grid, 256, 0, stream>>>(
            xout, stats, gamma + l * 3 * H, beta + l * 3 * H, seg, out, l + 1);
        float* t = xin; xin = xout; xout = t;
    }

    // final: divide per-graph sums by counts
    scale_out_kernel<<<(N_GRAPHS * 3 * 4 * H + 255) / 256, 256, 0, stream>>>(out, seg);
}

// Round 4
// 1099.334 us; speedup vs baseline: 2.5011x; 1.2602x over previous
//
#include <hip/hip_runtime.h>

#define N_NODES 50000
#define N_EDGES 400000
#define N_GRAPHS 64
#define EMB 64
#define H 128
#define EPS 1e-5f

typedef __attribute__((ext_vector_type(8))) short bf16x8;
typedef __attribute__((ext_vector_type(4))) float f32x4;

__device__ __forceinline__ unsigned short f2b(float f) {
    unsigned int u = __builtin_bit_cast(unsigned int, f);
    unsigned int r = (u + 0x7fff + ((u >> 16) & 1)) >> 16;  // RNE
    return (unsigned short)r;
}

// ---------------- CSR build ----------------

__global__ void count_deg_kernel(const int* __restrict__ dst, int* __restrict__ deg) {
    int rel = blockIdx.y;
    int e = blockIdx.x * 256 + threadIdx.x;
    if (e < N_EDGES) atomicAdd(&deg[rel * N_NODES + dst[rel * N_EDGES + e]], 1);
}

__global__ void scan_kernel(const int* __restrict__ deg, int* __restrict__ row_ptr) {
    int rel = blockIdx.x;
    const int* d = deg + rel * N_NODES;
    int* rp = row_ptr + rel * (N_NODES + 1);
    __shared__ int sm[1024];
    __shared__ int carry;
    if (threadIdx.x == 0) carry = 0;
    __syncthreads();
    for (int base = 0; base < N_NODES; base += 1024) {
        int i = base + (int)threadIdx.x;
        int v = (i < N_NODES) ? d[i] : 0;
        sm[threadIdx.x] = v;
        __syncthreads();
        for (int off = 1; off < 1024; off <<= 1) {
            int t = (threadIdx.x >= off) ? sm[threadIdx.x - off] : 0;
            __syncthreads();
            sm[threadIdx.x] += t;
            __syncthreads();
        }
        int incl = sm[threadIdx.x];
        if (i < N_NODES) rp[i] = carry + incl - v;
        __syncthreads();
        if (threadIdx.x == 1023) carry += incl;
        __syncthreads();
    }
    if (threadIdx.x == 0) rp[N_NODES] = carry;
}

__global__ void init_cur_kernel(const int* __restrict__ row_ptr, int* __restrict__ cur) {
    int i = blockIdx.x * 256 + threadIdx.x;
    if (i < 3 * N_NODES) {
        int rel = i / N_NODES, n = i - rel * N_NODES;
        cur[i] = row_ptr[rel * (N_NODES + 1) + n];
    }
}

__global__ void fill_kernel(const int* __restrict__ src, const int* __restrict__ dst,
                            int* __restrict__ cur, int* __restrict__ edge_src) {
    int rel = blockIdx.y;
    int e = blockIdx.x * 256 + threadIdx.x;
    if (e < N_EDGES) {
        int dn = dst[rel * N_EDGES + e];
        int pos = atomicAdd(&cur[rel * N_NODES + dn], 1);
        edge_src[rel * N_EDGES + pos] = src[rel * N_EDGES + e];
    }
}

// ---------------- Embedding gather -> bf16 x0 ----------------

__global__ void embed_kernel(const int* __restrict__ h_idx, const int* __restrict__ p_idx,
                             const int* __restrict__ hp_idx,
                             const float* __restrict__ emb_h, const float* __restrict__ emb_p,
                             const float* __restrict__ emb_hp,
                             unsigned short* __restrict__ x) {
    int rel = blockIdx.y;
    int i = blockIdx.x * 256 + threadIdx.x;  // 8-col units
    if (i >= N_NODES * EMB / 8) return;
    int n = i / (EMB / 8), c8 = (i % (EMB / 8)) * 8;
    const int* idx = rel == 0 ? h_idx : (rel == 1 ? p_idx : hp_idx);
    const float* emb = rel == 0 ? emb_h : (rel == 1 ? emb_p : emb_hp);
    const float* e = emb + (size_t)idx[n] * EMB + c8;
    unsigned short o[8];
#pragma unroll
    for (int j = 0; j < 8; j++) o[j] = f2b(e[j]);
    *(uint4*)&x[(size_t)rel * N_NODES * EMB + (size_t)n * EMB + c8] = *(uint4*)o;
}

// ---------------- Neighbor mean aggregation (bf16 gather, BN-affine fold) ----------------
// Output nmean has ld = DIN. For deg==0 output is exactly 0 (reference semantics).

template <int DIN, bool FOLD>
__global__ __launch_bounds__(256) void aggregate_kernel(
        const unsigned short* __restrict__ x, int ldx,
        const int* __restrict__ row_ptr, const int* __restrict__ edge_src,
        const float* __restrict__ st,
        unsigned short* __restrict__ nmean) {
    const int TPN = DIN / 8;
    int rel = blockIdx.y;
    int node = blockIdx.x * (256 / TPN) + threadIdx.x / TPN;
    int c8 = (threadIdx.x % TPN) * 8;
    if (node >= N_NODES) return;
    const int* rp = row_ptr + rel * (N_NODES + 1);
    const int* es = edge_src + rel * N_EDGES;
    const unsigned short* xr = x + (size_t)rel * N_NODES * ldx;
    int s0 = rp[node], s1 = rp[node + 1];
    float acc[8];
#pragma unroll
    for (int j = 0; j < 8; j++) acc[j] = 0.f;

#define ACCUM(V)                                                                      \
    {                                                                                 \
        unsigned int w[4] = {(V).x, (V).y, (V).z, (V).w};                             \
        _Pragma("unroll") for (int j = 0; j < 4; j++) {                               \
            acc[2 * j] += __builtin_bit_cast(float, w[j] << 16);                      \
            acc[2 * j + 1] += __builtin_bit_cast(float, w[j] & 0xffff0000u);          \
        }                                                                             \
    }

    int e = s0;
    for (; e + 4 <= s1; e += 4) {
        int i0 = es[e], i1 = es[e + 1], i2 = es[e + 2], i3 = es[e + 3];
        uint4 v0 = *(const uint4*)&xr[(size_t)i0 * ldx + c8];
        uint4 v1 = *(const uint4*)&xr[(size_t)i1 * ldx + c8];
        uint4 v2 = *(const uint4*)&xr[(size_t)i2 * ldx + c8];
        uint4 v3 = *(const uint4*)&xr[(size_t)i3 * ldx + c8];
        ACCUM(v0) ACCUM(v1) ACCUM(v2) ACCUM(v3)
    }
    for (; e < s1; e++) {
        uint4 v0 = *(const uint4*)&xr[(size_t)es[e] * ldx + c8];
        ACCUM(v0)
    }
#undef ACCUM
    int deg = s1 - s0;
    float inv = 1.f / (float)max(deg, 1);
    unsigned short o[8];
#pragma unroll
    for (int j = 0; j < 8; j++) {
        float m = acc[j] * inv;
        if (FOLD) {
            float s = st[rel * 2 * H + c8 + j];
            float t = st[rel * 2 * H + H + c8 + j];
            m = s * m + t;
        }
        o[j] = (deg > 0) ? f2b(m) : (unsigned short)0;
    }
    *(uint4*)&nmean[((size_t)rel * N_NODES + node) * DIN + c8] = *(uint4*)o;
}

// ---- MFMA GEMM: hp = PReLU([x | nmean] @ Wbt^T + bias); fp32 col stats ----
// KTOT = 2*KX (self KX | neigh KX). nmean ld = KX. Block 128x128, 4 waves (2x2),
// each wave 64x64 via 4x4 16x16x32 bf16 fragments.
// For KX==H, out may alias nmean (block writes only rows it read, same ld).

template <int KX>
__global__ __launch_bounds__(256) void gemm_kernel(
        const unsigned short* __restrict__ x,      // [N][KX] bf16 self input
        const unsigned short* __restrict__ nmean,  // [N][KX] bf16
        const unsigned short* __restrict__ Wbt,    // [rel][H cols][2*KX] bf16
        const float* __restrict__ bias,            // [rel][H]
        const float* __restrict__ alpha,           // [rel][H]
        unsigned short* __restrict__ out,          // [rel][N][H] bf16 (pre-BN)
        float* __restrict__ stats) {
    const int KTOT = 2 * KX;
    int rel = blockIdx.y;
    int row0 = blockIdx.x * 128;
    const unsigned short* xr = x + (size_t)rel * N_NODES * KX;
    const unsigned short* nm = nmean + (size_t)rel * N_NODES * KX;
    const unsigned short* W = Wbt + (size_t)rel * H * KTOT;
    unsigned short* o = out + (size_t)rel * N_NODES * H;

    __shared__ __align__(16) short At[128][40];
    __shared__ __align__(16) short Bt[128][40];

    int tid = threadIdx.x;
    int lane = tid & 63;
    int wave = tid >> 6;
    int wr = wave >> 1, wc = wave & 1;
    int l15 = lane & 15;
    int koff = (lane >> 4) * 8;

    f32x4 acc[4][4];
#pragma unroll
    for (int m = 0; m < 4; m++)
#pragma unroll
        for (int n = 0; n < 4; n++) acc[m][n] = (f32x4){0.f, 0.f, 0.f, 0.f};

    int seg = tid & 3;
    int rloc = tid >> 2;

    for (int kc = 0; kc < KTOT; kc += 32) {
        const unsigned short* Asrc;
        int kb;
        if (kc < KX) { Asrc = xr; kb = kc; }
        else         { Asrc = nm; kb = kc - KX; }
#pragma unroll
        for (int i = 0; i < 2; i++) {
            int r = i * 64 + rloc;
            int gr = row0 + r;
            uint4 v = make_uint4(0u, 0u, 0u, 0u);
            if (gr < N_NODES) v = *(const uint4*)&Asrc[(size_t)gr * KX + kb + seg * 8];
            *(uint4*)&At[r][seg * 8] = v;
        }
#pragma unroll
        for (int i = 0; i < 2; i++) {
            int c = i * 64 + rloc;
            *(uint4*)&Bt[c][seg * 8] = *(const uint4*)&W[(size_t)c * KTOT + kc + seg * 8];
        }
        __syncthreads();
        bf16x8 a[4], b[4];
#pragma unroll
        for (int m = 0; m < 4; m++) a[m] = *(const bf16x8*)&At[wr * 64 + m * 16 + l15][koff];
#pragma unroll
        for (int n = 0; n < 4; n++) b[n] = *(const bf16x8*)&Bt[wc * 64 + n * 16 + l15][koff];
#pragma unroll
        for (int m = 0; m < 4; m++)
#pragma unroll
            for (int n = 0; n < 4; n++)
                acc[m][n] = __builtin_amdgcn_mfma_f32_16x16x32_bf16(a[m], b[n], acc[m][n], 0, 0, 0);
        __syncthreads();
    }

    // epilogue: bias + PReLU, bf16 store, fp32 column stats
    float bs[4], as_[4];
#pragma unroll
    for (int n = 0; n < 4; n++) {
        int col = wc * 64 + n * 16 + l15;
        bs[n] = bias[rel * H + col];
        as_[n] = alpha[rel * H + col];
    }
    float csum[4] = {0.f, 0.f, 0.f, 0.f}, cssq[4] = {0.f, 0.f, 0.f, 0.f};
    int rbase = row0 + wr * 64 + (lane >> 4) * 4;
#pragma unroll
    for (int m = 0; m < 4; m++) {
#pragma unroll
        for (int j = 0; j < 4; j++) {
            int r = rbase + m * 16 + j;
            if (r >= N_NODES) continue;
#pragma unroll
            for (int n = 0; n < 4; n++) {
                float v = acc[m][n][j] + bs[n];
                v = v > 0.f ? v : as_[n] * v;
                o[(size_t)r * H + wc * 64 + n * 16 + l15] = f2b(v);
                csum[n] += v;
                cssq[n] += v * v;
            }
        }
    }
    __syncthreads();
    float* smS = (float*)&At[0][0];  // 128 cols x 8 contributors = 4 KB
    float* smQ = (float*)&Bt[0][0];
    int contrib = wr * 4 + (lane >> 4);
#pragma unroll
    for (int n = 0; n < 4; n++) {
        int col = wc * 64 + n * 16 + l15;
        smS[col * 8 + contrib] = csum[n];
        smQ[col * 8 + contrib] = cssq[n];
    }
    __syncthreads();
    if (tid < 128) {
        float s = 0.f, q = 0.f;
#pragma unroll
        for (int i = 0; i < 8; i++) { s += smS[tid * 8 + i]; q += smQ[tid * 8 + i]; }
        atomicAdd(&stats[rel * 256 + tid], s);
        atomicAdd(&stats[rel * 256 + 128 + tid], q);
    }
}

// ---------------- BN stats -> affine (s,t) ----------------

__global__ void finalize_kernel(const float* __restrict__ stats,
                                const float* __restrict__ gamma, const float* __restrict__ beta,
                                float* __restrict__ st) {
    int rel = blockIdx.x, c = threadIdx.x;
    const float invN = 1.f / N_NODES;
    float mu = stats[rel * 256 + c] * invN;
    float var = stats[rel * 256 + 128 + c] * invN - mu * mu;
    float s = gamma[rel * H + c] * rsqrtf(var + EPS);
    st[rel * 2 * H + c] = s;
    st[rel * 2 * H + H + c] = beta[rel * H + c] - mu * s;
}

// ---------------- Weight prep ----------------
// Layer 1: [rel][col][128] (self 64 | neigh 64)

__global__ void prep1_kernel(const float* __restrict__ Wself, const float* __restrict__ Wneigh,
                             unsigned short* __restrict__ Wbt) {
    int idx = blockIdx.x * 256 + threadIdx.x;
    if (idx >= 3 * H * 128) return;
    int rel = idx / (H * 128), rem = idx % (H * 128);
    int c = rem / 128, k = rem % 128;
    float v = (k < 64) ? Wself[((size_t)rel * 64 + k) * H + c]
                       : Wneigh[((size_t)rel * 64 + (k - 64)) * H + c];
    Wbt[idx] = f2b(v);
}

// Layers 2-4: fold s into self rows -> [rel][col][256] (self 128 | neigh 128)

__global__ void prep_w_kernel(const float* __restrict__ Wself, const float* __restrict__ Wneigh,
                              const float* __restrict__ st, unsigned short* __restrict__ Wbt) {
    int idx = blockIdx.x * 256 + threadIdx.x;
    if (idx >= 3 * H * 256) return;
    int rel = idx / (H * 256), rem = idx % (H * 256);
    int c = rem / 256, k = rem % 256;
    float v;
    if (k < 128) v = st[rel * 2 * H + k] * Wself[((size_t)rel * H + k) * H + c];
    else         v = Wneigh[((size_t)rel * H + (k - 128)) * H + c];
    Wbt[idx] = f2b(v);
}

__global__ void prep_bias_kernel(const float* __restrict__ Wself, const float* __restrict__ b,
                                 const float* __restrict__ st, float* __restrict__ biasp) {
    int rel = blockIdx.x, c = threadIdx.x;
    const float* t = st + rel * 2 * H + H;
    float s = b[rel * H + c];
    for (int k = 0; k < H; k++) s += t[k] * Wself[((size_t)rel * H + k) * H + c];
    biasp[rel * H + c] = s;
}

// ---------------- Readout: per-graph sums of raw hp (affine applied at end) ----------------

__global__ __launch_bounds__(256) void readout_kernel(
        const unsigned short* __restrict__ hp, const int* __restrict__ seg,
        float* __restrict__ out, int layer) {
    int rel = blockIdx.y;
    int c8 = (threadIdx.x & 15) * 8;
    int roff = threadIdx.x >> 4;  // 0..15
    int row0 = blockIdx.x * 256;
    const unsigned short* h = hp + (size_t)rel * N_NODES * H;
    const int* sg = seg + rel * N_NODES;
    int curg = -1;
    float run[8];
#pragma unroll
    for (int j = 0; j < 8; j++) run[j] = 0.f;
    int rend = min(row0 + 256, N_NODES);
    for (int r = row0 + roff; r < rend; r += 16) {
        uint4 v = *(const uint4*)&h[(size_t)r * H + c8];
        unsigned int w[4] = {v.x, v.y, v.z, v.w};
        int g = sg[r];
        if (g != curg) {
            if (curg >= 0) {
                float* ob = out + curg * (3 * 4 * H) + rel * (4 * H) + layer * H + c8;
#pragma unroll
                for (int j = 0; j < 8; j++) atomicAdd(ob + j, run[j]);
            }
            curg = g;
#pragma unroll
            for (int j = 0; j < 8; j++) run[j] = 0.f;
        }
#pragma unroll
        for (int j = 0; j < 4; j++) {
            run[2 * j] += __builtin_bit_cast(float, w[j] << 16);
            run[2 * j + 1] += __builtin_bit_cast(float, w[j] & 0xffff0000u);
        }
    }
    if (curg >= 0) {
        float* ob = out + curg * (3 * 4 * H) + rel * (4 * H) + layer * H + c8;
#pragma unroll
        for (int j = 0; j < 8; j++) atomicAdd(ob + j, run[j]);
    }
}

// ---------------- Final: mean + BN affine ----------------

__global__ void scale_out_kernel(float* __restrict__ out, const int* __restrict__ seg,
                                 const float* __restrict__ st_all) {
    int i = blockIdx.x * 256 + threadIdx.x;
    if (i >= N_GRAPHS * 3 * 4 * H) return;
    int g = i / (3 * 4 * H), k = i % (3 * 4 * H);
    int rel = k / (4 * H), rem = k % (4 * H), layer = rem / H, c = rem % H;
    const int* sg = seg + rel * N_NODES;
    int lo = 0, hi = N_NODES;
    while (lo < hi) { int m = (lo + hi) >> 1; if (sg[m] < g) lo = m + 1; else hi = m; }
    int start = lo;
    hi = N_NODES;
    while (lo < hi) { int m = (lo + hi) >> 1; if (sg[m] <= g) lo = m + 1; else hi = m; }
    int cnt = lo - start;
    float mean = out[i] / (float)max(cnt, 1);
    const float* st = st_all + ((size_t)layer * 3 + rel) * 2 * H;
    out[i] = st[c] * mean + st[H + c];
}

// ---------------- Orchestration ----------------

extern "C" void kernel_launch(void* const* d_in, const int* in_sizes, int n_in,
                              void* d_out, int out_size, void* d_ws, size_t ws_size,
                              hipStream_t stream) {
    const int* h_idx = (const int*)d_in[0];
    const int* p_idx = (const int*)d_in[1];
    const int* hp_idx = (const int*)d_in[2];
    const int* src = (const int*)d_in[3];
    const int* dst = (const int*)d_in[4];
    const int* seg = (const int*)d_in[5];
    const float* emb_h = (const float*)d_in[6];
    const float* emb_p = (const float*)d_in[7];
    const float* emb_hp = (const float*)d_in[8];
    const float* W1_self = (const float*)d_in[9];
    const float* W1_neigh = (const float*)d_in[10];
    const float* b1 = (const float*)d_in[11];
    const float* a1 = (const float*)d_in[12];
    const float* gamma1 = (const float*)d_in[13];
    const float* beta1 = (const float*)d_in[14];
    const float* W_self = (const float*)d_in[15];
    const float* W_neigh = (const float*)d_in[16];
    const float* b = (const float*)d_in[17];
    const float* a = (const float*)d_in[18];
    const float* gamma = (const float*)d_in[19];
    const float* beta = (const float*)d_in[20];
    float* out = (float*)d_out;

    // workspace
    char* p = (char*)d_ws;
    unsigned short* x0 = (unsigned short*)p; p += (size_t)3 * N_NODES * EMB * 2;   // 19.2 MB
    unsigned short* hpA = (unsigned short*)p; p += (size_t)3 * N_NODES * H * 2;    // 38.4 MB
    unsigned short* hpB = (unsigned short*)p; p += (size_t)3 * N_NODES * H * 2;    // 38.4 MB
    unsigned short* Wbt1 = (unsigned short*)p; p += (size_t)3 * H * 128 * 2;
    unsigned short* Wbt = (unsigned short*)p; p += (size_t)3 * H * 256 * 2;
    float* biasp = (float*)p; p += 3 * H * sizeof(float);
    float* st_all = (float*)p; p += 4 * 3 * 2 * H * sizeof(float);
    float* stats = (float*)p; p += 3 * 256 * sizeof(float);
    int* deg = (int*)p; p += (size_t)3 * N_NODES * 4;
    int* row_ptr = (int*)p; p += (size_t)3 * (N_NODES + 1) * 4;
    int* cur = (int*)p; p += (size_t)3 * N_NODES * 4;
    int* edge_src = (int*)p; p += (size_t)3 * N_EDGES * 4;

    hipMemsetAsync(out, 0, (size_t)N_GRAPHS * 3 * 4 * H * sizeof(float), stream);

    // CSR build
    hipMemsetAsync(deg, 0, (size_t)3 * N_NODES * 4, stream);
    dim3 eb((N_EDGES + 255) / 256, 3);
    count_deg_kernel<<<eb, 256, 0, stream>>>(dst, deg);
    scan_kernel<<<3, 1024, 0, stream>>>(deg, row_ptr);
    init_cur_kernel<<<(3 * N_NODES + 255) / 256, 256, 0, stream>>>(row_ptr, cur);
    fill_kernel<<<eb, 256, 0, stream>>>(src, dst, cur, edge_src);

    embed_kernel<<<dim3((N_NODES * EMB / 8 + 255) / 256, 3), 256, 0, stream>>>(
        h_idx, p_idx, hp_idx, emb_h, emb_p, emb_hp, x0);
    prep1_kernel<<<(3 * H * 128 + 255) / 256, 256, 0, stream>>>(W1_self, W1_neigh, Wbt1);

    dim3 gemm_grid((N_NODES + 127) / 128, 3);
    dim3 ro_grid((N_NODES + 255) / 256, 3);

    // ---- layer 1 (self K=64 from x0, neigh K=64, nmean ld=64 in hpB; out hpA) ----
    aggregate_kernel<64, false><<<dim3((N_NODES + 31) / 32, 3), 256, 0, stream>>>(
        x0, EMB, row_ptr, edge_src, nullptr, hpB);
    hipMemsetAsync(stats, 0, 3 * 256 * 4, stream);
    gemm_kernel<64><<<gemm_grid, 256, 0, stream>>>(x0, hpB, Wbt1, b1, a1, hpA, stats);
    finalize_kernel<<<3, H, 0, stream>>>(stats, gamma1, beta1, st_all);
    readout_kernel<<<ro_grid, 256, 0, stream>>>(hpA, seg, out, 0);

    // ---- layers 2-4 (K=128, nmean ld=128, out aliases nmean) ----
    unsigned short* xin = hpA;
    unsigned short* xout = hpB;
    for (int l = 0; l < 3; l++) {
        const float* st_prev = st_all + (size_t)l * 3 * 2 * H;
        prep_w_kernel<<<(3 * H * 256 + 255) / 256, 256, 0, stream>>>(
            W_self + (size_t)l * 3 * H * H, W_neigh + (size_t)l * 3 * H * H, st_prev, Wbt);
        prep_bias_kernel<<<3, H, 0, stream>>>(
            W_self + (size_t)l * 3 * H * H, b + (size_t)l * 3 * H, st_prev, biasp);
        aggregate_kernel<128, true><<<dim3((N_NODES + 15) / 16, 3), 256, 0, stream>>>(
            xin, H, row_ptr, edge_src, st_prev, xout);
        hipMemsetAsync(stats, 0, 3 * 256 * 4, stream);
        gemm_kernel<128><<<gemm_grid, 256, 0, stream>>>(
            xin, xout, Wbt, biasp, a + (size_t)l * 3 * H, xout, stats);
        finalize_kernel<<<3, H, 0, stream>>>(
            stats, gamma + (size_t)l * 3 * H, beta + (size_t)l * 3 * H,
            st_all + (size_t)(l + 1) * 3 * 2 * H);
        readout_kernel<<<ro_grid, 256, 0, stream>>>(xout, seg, out, l + 1);
        unsigned short* t = xin; xin = xout; xout = t;
    }

    scale_out_kernel<<<(N_GRAPHS * 3 * 4 * H + 255) / 256, 256, 0, stream>>>(out, seg, st_all);
}